// Round 2
// baseline (326.950 us; speedup 1.0000x reference)
//
#include <hip/hip_runtime.h>
#include <hip/hip_bf16.h>
#include <cstdint>
#include <cstddef>

typedef __hip_bfloat16 bf16;
typedef float  floatx4 __attribute__((ext_vector_type(4)));
typedef __bf16 bf16x8  __attribute__((ext_vector_type(8)));

typedef __attribute__((address_space(1))) void as1_void;
typedef __attribute__((address_space(3))) void as3_void;

constexpr int Bn = 4, Ln = 2048, Cn = 1024;

__device__ __forceinline__ void store_one(float* p, float v) { *p = v; }
__device__ __forceinline__ void store_one(bf16*  p, float v) { *p = __float2bfloat16(v); }

// ---------------------------------------------------------------------------
// Generic bf16 BT-GEMM: C[m][n] = cscale * sum_k A[m][k] * B[n][k]
// 128x128 tile / block (256 thr, 4 waves, each wave 64x64 = 4x4 mfma 16x16x32)
// CAUSAL: 0 = none, 1 = skip tiles with n0 > m0 (S=QK^T), 2 = clamp K to m0+128 (PV)
// LDS layout: row r (0..127 per matrix), k-chunk c (16B) stored at slot
//   r*4 + (c ^ (r&3))  -- XOR swizzle breaks the 64B-row-stride bank aliasing.
// Staging side realizes the swizzle by permuting the *global* chunk each lane
// fetches (global_load_lds LDS dest is lane-linear and can't be permuted).
// ---------------------------------------------------------------------------
template <typename OutT, int CAUSAL>
__global__ __launch_bounds__(256)
void gemm_bt(const bf16* __restrict__ A, const bf16* __restrict__ B, OutT* __restrict__ C,
             int M, int N, int K, int lda, int ldb, int ldc,
             long long sA, long long sB, long long sC, float cscale)
{
    const int bz = blockIdx.z;
    A += bz * sA;  B += bz * sB;  C += bz * sC;
    const int m0 = blockIdx.x * 128;
    const int n0 = blockIdx.y * 128;
    if (CAUSAL == 1 && n0 > m0) return;          // fully-masked tile, never read
    int Keff = K;
    if (CAUSAL == 2) Keff = (K < m0 + 128) ? K : (m0 + 128);

    __shared__ __align__(16) bf16 smem[2 * 128 * 32];   // As (8KB) then Bs (8KB)

    const int tid  = threadIdx.x;
    const int lane = tid & 63;
    const int quad = lane >> 4;      // 0..3 = k-chunk for fragments
    const int lr   = lane & 15;      // row-in-16 for A/B frags; col for C
    const int wave = tid >> 6;
    const int wm   = (wave >> 1) * 64;
    const int wn   = (wave & 1) * 64;

    floatx4 acc[4][4];
#pragma unroll
    for (int i = 0; i < 4; ++i)
#pragma unroll
        for (int j = 0; j < 4; ++j) { floatx4 z = {0.f, 0.f, 0.f, 0.f}; acc[i][j] = z; }

    // staging: 1024 16B chunks; LDS slot = chunk = it*256+tid (lane-linear).
    // global chunk fetched = swizzled so slot r*4+s holds global chunk s^(r&3).
    const bf16* gbase[4];
    int ldsoff[4];
#pragma unroll
    for (int it = 0; it < 4; ++it) {
        int chunk = it * 256 + tid;
        ldsoff[it] = __builtin_amdgcn_readfirstlane((chunk & ~63) * 16);
        int kc = (chunk & 3) ^ ((chunk >> 2) & 3);   // XOR swizzle
        if (chunk < 512) {               // A side: 4 chunks per 32-elem row
            int m = chunk >> 2;
            gbase[it] = A + (size_t)(m0 + m) * lda + kc * 8;
        } else {                         // B side
            int c2 = chunk - 512;
            int n = c2 >> 2;
            gbase[it] = B + (size_t)(n0 + n) * ldb + kc * 8;
        }
    }

    for (int k0 = 0; k0 < Keff; k0 += 32) {
        __syncthreads();
#pragma unroll
        for (int it = 0; it < 4; ++it) {
            uintptr_t ga = (uintptr_t)(gbase[it] + k0);
            uintptr_t la = (uintptr_t)((char*)smem + ldsoff[it]);
            __builtin_amdgcn_global_load_lds((const as1_void*)ga, (as3_void*)la, 16, 0, 0);
        }
        __syncthreads();

        const bf16* As = smem;
        const bf16* Bs = smem + 128 * 32;
        const int sw = (quad ^ (lr & 3)) * 8;        // swizzled element offset
        bf16x8 afrag[4], bfrag[4];
#pragma unroll
        for (int i = 0; i < 4; ++i)
            afrag[i] = *(const bf16x8*)(As + (size_t)(wm + i * 16 + lr) * 32 + sw);
#pragma unroll
        for (int j = 0; j < 4; ++j)
            bfrag[j] = *(const bf16x8*)(Bs + (size_t)(wn + j * 16 + lr) * 32 + sw);
#pragma unroll
        for (int i = 0; i < 4; ++i)
#pragma unroll
            for (int j = 0; j < 4; ++j)
                acc[i][j] = __builtin_amdgcn_mfma_f32_16x16x32_bf16(afrag[i], bfrag[j], acc[i][j], 0, 0, 0);
    }

    // epilogue: C/D layout col=lane&15, row=quad*4+r  (m89-verified)
#pragma unroll
    for (int i = 0; i < 4; ++i) {
        int row = m0 + wm + i * 16 + quad * 4;
#pragma unroll
        for (int j = 0; j < 4; ++j) {
            int col = n0 + wn + j * 16 + lr;
            OutT* cp = C + (size_t)row * ldc + col;
#pragma unroll
            for (int r = 0; r < 4; ++r)
                store_one(cp + (size_t)r * ldc, acc[i][j][r] * cscale);
        }
    }
}

// ---------------------------------------------------------------------------
// Causal softmax on bf16 S (scale already folded into GEMM2), in-place -> P.
// One block per row; only k < kmax = roundup(q+1,128) is touched (PV clamps
// its K-loop to exactly kmax for this row's tile, so beyond that is never read).
// ---------------------------------------------------------------------------
__device__ __forceinline__ float waveMax(float x) {
#pragma unroll
    for (int o = 32; o > 0; o >>= 1) x = fmaxf(x, __shfl_xor(x, o, 64));
    return x;
}
__device__ __forceinline__ float waveSum(float x) {
#pragma unroll
    for (int o = 32; o > 0; o >>= 1) x += __shfl_xor(x, o, 64);
    return x;
}

__global__ __launch_bounds__(256)
void softmax_causal(bf16* __restrict__ S)
{
    const long long row = blockIdx.x;            // b*L + q
    const int q = (int)(row & (Ln - 1));
    bf16* Srow = S + row * (long long)Ln;
    const int tid = threadIdx.x;
    const int lane = tid & 63, wave = tid >> 6;
    const int kmax = ((q >> 7) + 1) << 7;        // 128-aligned row extent
    const int nit  = (kmax + 255) >> 8;          // 1..8 tiles of 256

    float v[8];
    float m = -1e30f;
    for (int it = 0; it < nit; ++it) {
        int k = it * 256 + tid;
        float x = (k <= q) ? __bfloat162float(Srow[k]) : -1e30f;
        v[it] = x;
        m = fmaxf(m, x);
    }
    __shared__ float redm[4], reds[4];
    m = waveMax(m);
    if (lane == 0) redm[wave] = m;
    __syncthreads();
    m = fmaxf(fmaxf(redm[0], redm[1]), fmaxf(redm[2], redm[3]));

    float s = 0.f;
    for (int it = 0; it < nit; ++it) {
        int k = it * 256 + tid;
        float e = (k <= q) ? __expf(v[it] - m) : 0.f;
        v[it] = e;
        s += e;
    }
    s = waveSum(s);
    if (lane == 0) reds[wave] = s;
    __syncthreads();
    s = reds[0] + reds[1] + reds[2] + reds[3];
    float inv = 1.f / s;
    for (int it = 0; it < nit; ++it) {
        int k = it * 256 + tid;
        if (k < kmax) Srow[k] = __float2bfloat16(v[it] * inv);
    }
}

// ---------------------------------------------------------------------------
// VT[b][c][l] = qkv[b][l][2C + c]   (32x32 tiles via LDS)
// ---------------------------------------------------------------------------
__global__ __launch_bounds__(256)
void transpose_v(const bf16* __restrict__ qkv, bf16* __restrict__ VT)
{
    __shared__ bf16 t[32][33];
    const int b = blockIdx.z;
    const int l0 = blockIdx.x * 32, c0 = blockIdx.y * 32;
    const int tx = threadIdx.x & 31, ty0 = threadIdx.x >> 5;   // ty0 in 0..7
    const bf16* src = qkv + ((size_t)(b * Ln + l0) * (3 * Cn)) + 2 * Cn + c0;
#pragma unroll
    for (int p = 0; p < 4; ++p) {
        int ly = ty0 + p * 8;
        t[ly][tx] = src[(size_t)ly * (3 * Cn) + tx];
    }
    __syncthreads();
    bf16* dst = VT + ((size_t)b * Cn + c0) * Ln + l0;
#pragma unroll
    for (int p = 0; p < 4; ++p) {
        int cy = ty0 + p * 8;
        dst[(size_t)cy * Ln + tx] = t[tx][cy];
    }
}

// ---------------------------------------------------------------------------
// One launch casting all three fp32 inputs to bf16 (float4-granular).
// Region sizes in float4 units: X = 2097152, Wqkv = 786432, Wout = 262144.
// ---------------------------------------------------------------------------
__global__ __launch_bounds__(256)
void cast_all(const float* __restrict__ X, const float* __restrict__ Wq,
              const float* __restrict__ Wo,
              bf16* __restrict__ Xb, bf16* __restrict__ Wqb, bf16* __restrict__ Wob)
{
    int i = blockIdx.x * 256 + threadIdx.x;
    const float* src; bf16* dst; int off;
    if (i < 2097152)                { src = X;  dst = Xb;  off = i; }
    else if (i < 2097152 + 786432)  { src = Wq; dst = Wqb; off = i - 2097152; }
    else                            { src = Wo; dst = Wob; off = i - 2883584; }
    float4 f = ((const float4*)src)[off];
    bf16 o0 = __float2bfloat16(f.x), o1 = __float2bfloat16(f.y);
    bf16 o2 = __float2bfloat16(f.z), o3 = __float2bfloat16(f.w);
    ushort4 u;
    u.x = *(unsigned short*)&o0; u.y = *(unsigned short*)&o1;
    u.z = *(unsigned short*)&o2; u.w = *(unsigned short*)&o3;
    *(ushort4*)(dst + (size_t)off * 4) = u;
}

// ---------------------------------------------------------------------------
extern "C" void kernel_launch(void* const* d_in, const int* in_sizes, int n_in,
                              void* d_out, int out_size, void* d_ws, size_t ws_size,
                              hipStream_t stream)
{
    const float* X    = (const float*)d_in[0];   // (B,L,C)
    const float* Wqkv = (const float*)d_in[1];   // (3C,C)
    const float* Wout = (const float*)d_in[2];   // (C,C)
    float* out = (float*)d_out;                  // (B,L,C) fp32

    char* ws = (char*)d_ws;
    const size_t MiB = 1024ull * 1024ull;
    // ws layout (Xb aliases Sbuf: GEMM1 reads Xb strictly before GEMM2 writes S)
    bf16* Sbuf = (bf16*)(ws + 0);                // 4*2048*2048*2 = 32 MiB (P in place)
    bf16* Xb   = (bf16*)(ws + 0);                // 16 MiB, dead after GEMM1
    bf16* QKV  = (bf16*)(ws + 32 * MiB);         // 48 MiB
    bf16* VT   = (bf16*)(ws + 80 * MiB);         // 16 MiB
    bf16* Wqb  = (bf16*)(ws + 96 * MiB);         // 6 MiB
    bf16* Wob  = (bf16*)(ws + 102 * MiB);        // 2 MiB
    bf16* Obuf = (bf16*)(ws + 104 * MiB);        // 16 MiB   (total 120 MiB)

    // casts to bf16 (one launch)
    cast_all<<<dim3((2097152 + 786432 + 262144) / 256), 256, 0, stream>>>(
        X, Wqkv, Wout, Xb, Wqb, Wob);

    // 1) qkv = Xb @ Wqb^T   (8192 x 3072, K=1024)
    gemm_bt<bf16, 0><<<dim3(64, 24, 1), 256, 0, stream>>>(
        Xb, Wqb, QKV, 8192, 3072, 1024, 1024, 1024, 3072, 0, 0, 0, 1.0f);

    // V^T for the PV gemm
    transpose_v<<<dim3(Ln/32, Cn/32, Bn), 256, 0, stream>>>(QKV, VT);

    // 2) S = (Q @ K^T) * 1/sqrt(C), bf16 out (skip strictly-upper 128-tiles)
    gemm_bt<bf16, 1><<<dim3(16, 16, Bn), 256, 0, stream>>>(
        QKV, QKV + Cn, Sbuf, Ln, Ln, Cn, 3*Cn, 3*Cn, Ln,
        (long long)Ln * 3 * Cn, (long long)Ln * 3 * Cn, (long long)Ln * Ln, 0.03125f);

    // 3) causal softmax, P (bf16) in place, truncated to roundup(q+1,128)
    softmax_causal<<<dim3(Bn * Ln), 256, 0, stream>>>(Sbuf);

    // 4) O = P @ VT^T per batch (K clamped to m0+128; P zero-filled to there)
    gemm_bt<bf16, 2><<<dim3(16, 8, Bn), 256, 0, stream>>>(
        Sbuf, VT, Obuf, Ln, Cn, Ln, Ln, Ln, Cn,
        (long long)Ln * Ln, (long long)Cn * Ln, (long long)Ln * Cn, 1.0f);

    // 5) out = O @ Wob^T  (fp32 out)
    gemm_bt<float, 0><<<dim3(64, 8, 1), 256, 0, stream>>>(
        Obuf, Wob, out, Bn * Ln, Cn, Cn, Cn, Cn, Cn, 0, 0, 0, 1.0f);
}

// Round 3
// 322.082 us; speedup vs baseline: 1.0151x; 1.0151x over previous
//
#include <hip/hip_runtime.h>
#include <hip/hip_bf16.h>
#include <cstdint>
#include <cstddef>

typedef __hip_bfloat16 bf16;
typedef float  floatx4 __attribute__((ext_vector_type(4)));
typedef __bf16 bf16x8  __attribute__((ext_vector_type(8)));

typedef __attribute__((address_space(1))) void as1_void;
typedef __attribute__((address_space(3))) void as3_void;

constexpr int Bn = 4, Ln = 2048, Cn = 1024;

__device__ __forceinline__ void store_one(float* p, float v) { *p = v; }
__device__ __forceinline__ void store_one(bf16*  p, float v) { *p = __float2bfloat16(v); }

// ---------------------------------------------------------------------------
// Generic bf16 BT-GEMM: C[m][n] = cscale * sum_k A[m][k] * B[n][k]
// 128x128 tile / block (256 thr, 4 waves, each wave 64x64 = 4x4 mfma 16x16x32)
// MODE: 0 = plain
//       1 = causal triangular dispatch: blockIdx.x is a linear index into the
//           lower-triangle of 16x16 tiles; decode (i,j), m0=i*128, n0=j*128.
//       2 = K clamped to m0+128 (PV gemm; P rows are zero beyond the diagonal)
// NOTE (R2 post-mortem): do NOT xor-swizzle the LDS layout. SQ_LDS_BANK_CONFLICT
// here is exactly 4/ds_read_b128 with or without swizzle — it's the intrinsic
// multi-phase cost of wave64 b128 reads, not avoidable aliasing.
// ---------------------------------------------------------------------------
template <typename OutT, int MODE>
__global__ __launch_bounds__(256)
void gemm_bt(const bf16* __restrict__ A, const bf16* __restrict__ B, OutT* __restrict__ C,
             int M, int N, int K, int lda, int ldb, int ldc,
             long long sA, long long sB, long long sC, float cscale)
{
    const int bz = blockIdx.z;
    A += bz * sA;  B += bz * sB;  C += bz * sC;
    int m0, n0;
    if (MODE == 1) {
        int t = blockIdx.x;
        int i = (int)((sqrtf(8.f * t + 1.f) - 1.f) * 0.5f);
        while ((i + 1) * (i + 2) / 2 <= t) ++i;
        while (i * (i + 1) / 2 > t) --i;
        int j = t - i * (i + 1) / 2;
        m0 = i * 128;  n0 = j * 128;
    } else {
        m0 = blockIdx.x * 128;
        n0 = blockIdx.y * 128;
    }
    int Keff = K;
    if (MODE == 2) Keff = (K < m0 + 128) ? K : (m0 + 128);

    __shared__ __align__(16) bf16 smem[2 * 128 * 32];   // As (8KB) then Bs (8KB)

    const int tid  = threadIdx.x;
    const int lane = tid & 63;
    const int quad = lane >> 4;      // 0..3 = k-chunk for fragments
    const int lr   = lane & 15;      // row-in-16 for A/B frags; col for C
    const int wave = tid >> 6;
    const int wm   = (wave >> 1) * 64;
    const int wn   = (wave & 1) * 64;

    floatx4 acc[4][4];
#pragma unroll
    for (int i = 0; i < 4; ++i)
#pragma unroll
        for (int j = 0; j < 4; ++j) { floatx4 z = {0.f, 0.f, 0.f, 0.f}; acc[i][j] = z; }

    // staging: 1024 16B chunks; chunk = it*256 + tid, LDS linear (lane-order).
    const bf16* gbase[4];
    int ldsoff[4];
#pragma unroll
    for (int it = 0; it < 4; ++it) {
        int chunk = it * 256 + tid;
        ldsoff[it] = __builtin_amdgcn_readfirstlane((chunk & ~63) * 16);
        int kc = chunk & 3;
        if (chunk < 512) {               // A side: 4 chunks per 32-elem row
            int m = chunk >> 2;
            gbase[it] = A + (size_t)(m0 + m) * lda + kc * 8;
        } else {                         // B side
            int c2 = chunk - 512;
            int n = c2 >> 2;
            gbase[it] = B + (size_t)(n0 + n) * ldb + kc * 8;
        }
    }

    for (int k0 = 0; k0 < Keff; k0 += 32) {
        __syncthreads();
#pragma unroll
        for (int it = 0; it < 4; ++it) {
            uintptr_t ga = (uintptr_t)(gbase[it] + k0);
            uintptr_t la = (uintptr_t)((char*)smem + ldsoff[it]);
            __builtin_amdgcn_global_load_lds((const as1_void*)ga, (as3_void*)la, 16, 0, 0);
        }
        __syncthreads();

        const bf16* As = smem;
        const bf16* Bs = smem + 128 * 32;
        bf16x8 afrag[4], bfrag[4];
#pragma unroll
        for (int i = 0; i < 4; ++i)
            afrag[i] = *(const bf16x8*)(As + (size_t)(wm + i * 16 + lr) * 32 + quad * 8);
#pragma unroll
        for (int j = 0; j < 4; ++j)
            bfrag[j] = *(const bf16x8*)(Bs + (size_t)(wn + j * 16 + lr) * 32 + quad * 8);
#pragma unroll
        for (int i = 0; i < 4; ++i)
#pragma unroll
            for (int j = 0; j < 4; ++j)
                acc[i][j] = __builtin_amdgcn_mfma_f32_16x16x32_bf16(afrag[i], bfrag[j], acc[i][j], 0, 0, 0);
    }

    // epilogue: C/D layout col=lane&15, row=quad*4+r  (m89-verified)
#pragma unroll
    for (int i = 0; i < 4; ++i) {
        int row = m0 + wm + i * 16 + quad * 4;
#pragma unroll
        for (int j = 0; j < 4; ++j) {
            int col = n0 + wn + j * 16 + lr;
            OutT* cp = C + (size_t)row * ldc + col;
#pragma unroll
            for (int r = 0; r < 4; ++r)
                store_one(cp + (size_t)r * ldc, acc[i][j][r] * cscale);
        }
    }
}

// ---------------------------------------------------------------------------
// Causal softmax on bf16 S (1/sqrt(C) folded into GEMM2's epilogue), in-place.
// One block per row; only k < kmax = roundup(q+1,128) is touched (PV clamps
// its K-loop to exactly kmax for this row's tile; zero-fill to kmax).
// ---------------------------------------------------------------------------
__device__ __forceinline__ float waveMax(float x) {
#pragma unroll
    for (int o = 32; o > 0; o >>= 1) x = fmaxf(x, __shfl_xor(x, o, 64));
    return x;
}
__device__ __forceinline__ float waveSum(float x) {
#pragma unroll
    for (int o = 32; o > 0; o >>= 1) x += __shfl_xor(x, o, 64);
    return x;
}

__global__ __launch_bounds__(256)
void softmax_causal(bf16* __restrict__ S)
{
    const long long row = blockIdx.x;            // b*L + q
    const int q = (int)(row & (Ln - 1));
    bf16* Srow = S + row * (long long)Ln;
    const int tid = threadIdx.x;
    const int lane = tid & 63, wave = tid >> 6;
    const int kmax = ((q >> 7) + 1) << 7;        // 128-aligned row extent
    const int nit  = (kmax + 255) >> 8;          // 1..8 tiles of 256

    float v[8];
    float m = -1e30f;
    for (int it = 0; it < nit; ++it) {
        int k = it * 256 + tid;
        float x = (k <= q) ? __bfloat162float(Srow[k]) : -1e30f;
        v[it] = x;
        m = fmaxf(m, x);
    }
    __shared__ float redm[4], reds[4];
    m = waveMax(m);
    if (lane == 0) redm[wave] = m;
    __syncthreads();
    m = fmaxf(fmaxf(redm[0], redm[1]), fmaxf(redm[2], redm[3]));

    float s = 0.f;
    for (int it = 0; it < nit; ++it) {
        int k = it * 256 + tid;
        float e = (k <= q) ? __expf(v[it] - m) : 0.f;
        v[it] = e;
        s += e;
    }
    s = waveSum(s);
    if (lane == 0) reds[wave] = s;
    __syncthreads();
    s = reds[0] + reds[1] + reds[2] + reds[3];
    float inv = 1.f / s;
    for (int it = 0; it < nit; ++it) {
        int k = it * 256 + tid;
        if (k < kmax) Srow[k] = __float2bfloat16(v[it] * inv);
    }
}

// ---------------------------------------------------------------------------
// One launch casting all three fp32 inputs to bf16 (float4-granular).
// Region sizes in float4 units: X = 2097152, Wqkv = 786432, Wout = 262144.
// ---------------------------------------------------------------------------
__global__ __launch_bounds__(256)
void cast_all(const float* __restrict__ X, const float* __restrict__ Wq,
              const float* __restrict__ Wo,
              bf16* __restrict__ Xb, bf16* __restrict__ Wqb, bf16* __restrict__ Wob)
{
    int i = blockIdx.x * 256 + threadIdx.x;
    const float* src; bf16* dst; int off;
    if (i < 2097152)                { src = X;  dst = Xb;  off = i; }
    else if (i < 2097152 + 786432)  { src = Wq; dst = Wqb; off = i - 2097152; }
    else                            { src = Wo; dst = Wob; off = i - 2883584; }
    float4 f = ((const float4*)src)[off];
    bf16 o0 = __float2bfloat16(f.x), o1 = __float2bfloat16(f.y);
    bf16 o2 = __float2bfloat16(f.z), o3 = __float2bfloat16(f.w);
    ushort4 u;
    u.x = *(unsigned short*)&o0; u.y = *(unsigned short*)&o1;
    u.z = *(unsigned short*)&o2; u.w = *(unsigned short*)&o3;
    *(ushort4*)(dst + (size_t)off * 4) = u;
}

// ---------------------------------------------------------------------------
extern "C" void kernel_launch(void* const* d_in, const int* in_sizes, int n_in,
                              void* d_out, int out_size, void* d_ws, size_t ws_size,
                              hipStream_t stream)
{
    const float* X    = (const float*)d_in[0];   // (B,L,C)
    const float* Wqkv = (const float*)d_in[1];   // (3C,C)
    const float* Wout = (const float*)d_in[2];   // (C,C)
    float* out = (float*)d_out;                  // (B,L,C) fp32

    char* ws = (char*)d_ws;
    const size_t MiB = 1024ull * 1024ull;
    // ws layout. Xb aliases the low half of Sbuf: Xb's last read (gemm_V)
    // strictly precedes Sbuf's first write (gemm2).
    bf16* Sbuf = (bf16*)(ws + 0);                // 32 MiB (P written in place)
    bf16* Xb   = (bf16*)(ws + 0);                // 16 MiB, dead after gemm_V
    bf16* QK   = (bf16*)(ws + 32 * MiB);         // 8192 x 2048 = 32 MiB
    bf16* VT   = (bf16*)(ws + 64 * MiB);         // 1024 x 8192 = 16 MiB (ld 8192)
    bf16* Wqb  = (bf16*)(ws + 80 * MiB);         // 6 MiB (all of w_qkv)
    bf16* Wob  = (bf16*)(ws + 86 * MiB);         // 2 MiB
    bf16* Obuf = (bf16*)(ws + 88 * MiB);         // 16 MiB   (total 104 MiB)

    // casts to bf16 (one launch)
    cast_all<<<dim3((2097152 + 786432 + 262144) / 256), 256, 0, stream>>>(
        X, Wqkv, Wout, Xb, Wqb, Wob);

    // 1a) QK = Xb @ Wqkb^T   (8192 x 2048, K=1024): q cols 0..1023, k cols 1024..2047
    gemm_bt<bf16, 0><<<dim3(64, 16, 1), 256, 0, stream>>>(
        Xb, Wqb, QK, 8192, 2048, 1024, 1024, 1024, 2048, 0, 0, 0, 1.0f);

    // 1b) VT = Wvb @ Xb^T    (1024 x 8192, K=1024) -> V^T materialized directly,
    //     VT[c][b*L + l]; per-batch view via base offset b*2048, ld 8192.
    gemm_bt<bf16, 0><<<dim3(8, 64, 1), 256, 0, stream>>>(
        Wqb + 2048 * 1024, Xb, VT, 1024, 8192, 1024, 1024, 1024, 8192, 0, 0, 0, 1.0f);

    // 2) S = (Q @ K^T) * 1/sqrt(C), bf16 out; triangular dispatch (136 tiles/batch)
    gemm_bt<bf16, 1><<<dim3(136, 1, Bn), 256, 0, stream>>>(
        QK, QK + 1024, Sbuf, Ln, Ln, Cn, 2048, 2048, Ln,
        (long long)Ln * 2048, (long long)Ln * 2048, (long long)Ln * Ln, 0.03125f);

    // 3) causal softmax, P (bf16) in place, truncated to roundup(q+1,128)
    softmax_causal<<<dim3(Bn * Ln), 256, 0, stream>>>(Sbuf);

    // 4) O = P @ V  via VT (B rows are V^T rows); K clamped to m0+128
    gemm_bt<bf16, 2><<<dim3(16, 8, Bn), 256, 0, stream>>>(
        Sbuf, VT, Obuf, Ln, Cn, Ln, Ln, 8192, Cn,
        (long long)Ln * Ln, 2048ll, (long long)Ln * Cn, 1.0f);

    // 5) out = O @ Wob^T  (fp32 out)
    gemm_bt<float, 0><<<dim3(64, 8, 1), 256, 0, stream>>>(
        Obuf, Wob, out, Bn * Ln, Cn, Cn, Cn, Cn, Cn, 0, 0, 0, 1.0f);
}

// Round 4
// 271.931 us; speedup vs baseline: 1.2023x; 1.1844x over previous
//
#include <hip/hip_runtime.h>
#include <hip/hip_bf16.h>
#include <cstdint>
#include <cstddef>

typedef __hip_bfloat16 bf16;
typedef float  floatx4 __attribute__((ext_vector_type(4)));
typedef __bf16 bf16x8  __attribute__((ext_vector_type(8)));

typedef __attribute__((address_space(1))) void as1_void;
typedef __attribute__((address_space(3))) void as3_void;

constexpr int Bn = 4, Ln = 2048, Cn = 1024;

__device__ __forceinline__ void store_one(float* p, float v) { *p = v; }
__device__ __forceinline__ void store_one(bf16*  p, float v) { *p = __float2bfloat16(v); }

// ---------------------------------------------------------------------------
// Core bf16 BT-GEMM tile: C[m0..+128][n0..+128] = cscale * sum_k A[m][k]*B[n][k]
// 256 thr / 4 waves, each wave 64x64 via 4x4 mfma_f32_16x16x32_bf16.
// NOTE (R2 post-mortem): no LDS swizzle — SQ_LDS_BANK_CONFLICT is exactly
// 4/ds_read_b128 regardless (intrinsic wave64 b128 cost, not aliasing).
// ---------------------------------------------------------------------------
template <typename OutT>
__device__ __forceinline__ void gemm_core(
    const bf16* __restrict__ A, const bf16* __restrict__ B, OutT* __restrict__ C,
    int m0, int n0, int Keff, int lda, int ldb, int ldc, float cscale)
{
    __shared__ __align__(16) bf16 smem[2 * 128 * 32];   // As (8KB) then Bs (8KB)

    const int tid  = threadIdx.x;
    const int lane = tid & 63;
    const int quad = lane >> 4;
    const int lr   = lane & 15;
    const int wave = tid >> 6;
    const int wm   = (wave >> 1) * 64;
    const int wn   = (wave & 1) * 64;

    floatx4 acc[4][4];
#pragma unroll
    for (int i = 0; i < 4; ++i)
#pragma unroll
        for (int j = 0; j < 4; ++j) { floatx4 z = {0.f, 0.f, 0.f, 0.f}; acc[i][j] = z; }

    // staging: 1024 16B chunks; chunk = it*256 + tid, LDS linear (lane-order).
    const bf16* gbase[4];
    int ldsoff[4];
#pragma unroll
    for (int it = 0; it < 4; ++it) {
        int chunk = it * 256 + tid;
        ldsoff[it] = __builtin_amdgcn_readfirstlane((chunk & ~63) * 16);
        int kc = chunk & 3;
        if (chunk < 512) {               // A side: 4 chunks per 32-elem row
            int m = chunk >> 2;
            gbase[it] = A + (size_t)(m0 + m) * lda + kc * 8;
        } else {                         // B side
            int c2 = chunk - 512;
            int n = c2 >> 2;
            gbase[it] = B + (size_t)(n0 + n) * ldb + kc * 8;
        }
    }

    for (int k0 = 0; k0 < Keff; k0 += 32) {
        __syncthreads();
#pragma unroll
        for (int it = 0; it < 4; ++it) {
            uintptr_t ga = (uintptr_t)(gbase[it] + k0);
            uintptr_t la = (uintptr_t)((char*)smem + ldsoff[it]);
            __builtin_amdgcn_global_load_lds((const as1_void*)ga, (as3_void*)la, 16, 0, 0);
        }
        __syncthreads();

        const bf16* As = smem;
        const bf16* Bs = smem + 128 * 32;
        bf16x8 afrag[4], bfrag[4];
#pragma unroll
        for (int i = 0; i < 4; ++i)
            afrag[i] = *(const bf16x8*)(As + (size_t)(wm + i * 16 + lr) * 32 + quad * 8);
#pragma unroll
        for (int j = 0; j < 4; ++j)
            bfrag[j] = *(const bf16x8*)(Bs + (size_t)(wn + j * 16 + lr) * 32 + quad * 8);
#pragma unroll
        for (int i = 0; i < 4; ++i)
#pragma unroll
            for (int j = 0; j < 4; ++j)
                acc[i][j] = __builtin_amdgcn_mfma_f32_16x16x32_bf16(afrag[i], bfrag[j], acc[i][j], 0, 0, 0);
    }

    // epilogue: C/D layout col=lane&15, row=quad*4+r  (m89-verified)
#pragma unroll
    for (int i = 0; i < 4; ++i) {
        int row = m0 + wm + i * 16 + quad * 4;
#pragma unroll
        for (int j = 0; j < 4; ++j) {
            int col = n0 + wn + j * 16 + lr;
            OutT* cp = C + (size_t)row * ldc + col;
#pragma unroll
            for (int r = 0; r < 4; ++r)
                store_one(cp + (size_t)r * ldc, acc[i][j][r] * cscale);
        }
    }
}

// ---------------------------------------------------------------------------
// g1: blocks [0,64)    -> W2 = Wo·Wv   (1024x1024, K=1024)  [A=Wob, B=WvT]
//     blocks [64,1088) -> QK = Xb·Wqk^T (8192x2048, K=1024)
// ---------------------------------------------------------------------------
__global__ __launch_bounds__(256)
void g1_w2_qk(const bf16* __restrict__ Xb, const bf16* __restrict__ Wqkb,
              const bf16* __restrict__ Wob, const bf16* __restrict__ WvT,
              bf16* __restrict__ QK, bf16* __restrict__ W2)
{
    int i = blockIdx.x;
    if (i < 64) {
        int m0 = (i & 7) * 128, n0 = (i >> 3) * 128;
        gemm_core<bf16>(Wob, WvT, W2, m0, n0, 1024, 1024, 1024, 1024, 1.0f);
    } else {
        int j = i - 64;
        int m0 = (j & 63) * 128, n0 = (j >> 6) * 128;
        gemm_core<bf16>(Xb, Wqkb, QK, m0, n0, 1024, 1024, 1024, 2048, 1.0f);
    }
}

// ---------------------------------------------------------------------------
// g2: blocks [0,512)    -> VWT = W2·Xb^T (1024x8192, K=1024, ldc 8192)
//     blocks [512,1056) -> S = (Q·K^T)/32, triangular tiles (136/batch x 4)
// ---------------------------------------------------------------------------
__global__ __launch_bounds__(256)
void g2_vwt_s(const bf16* __restrict__ W2, const bf16* __restrict__ Xb,
              const bf16* __restrict__ QK, bf16* __restrict__ VWT,
              bf16* __restrict__ S)
{
    int i = blockIdx.x;
    if (i < 512) {
        int m0 = (i & 7) * 128, n0 = (i >> 3) * 128;
        gemm_core<bf16>(W2, Xb, VWT, m0, n0, 1024, 1024, 1024, 8192, 1.0f);
    } else {
        int j = i - 512;                 // 0..543
        int b = j / 136, t = j - b * 136;
        int ti = (int)((sqrtf(8.f * t + 1.f) - 1.f) * 0.5f);
        while ((ti + 1) * (ti + 2) / 2 <= t) ++ti;
        while (ti * (ti + 1) / 2 > t) --ti;
        int tj = t - ti * (ti + 1) / 2;
        const bf16* Aq = QK + (long long)b * Ln * 2048;
        const bf16* Bk = Aq + 1024;
        bf16* Sb = S + (long long)b * Ln * Ln;
        gemm_core<bf16>(Aq, Bk, Sb, ti * 128, tj * 128, 1024, 2048, 2048, Ln, 0.03125f);
    }
}

// ---------------------------------------------------------------------------
// g3: out = P · VW  (per batch, K clamped to m0+128), fp32 out.
// Heaviest m-tiles dispatched first (mt reversed) for makespan.
// ---------------------------------------------------------------------------
__global__ __launch_bounds__(256)
void g3_out(const bf16* __restrict__ P, const bf16* __restrict__ VWT,
            float* __restrict__ out)
{
    int i = blockIdx.x;                  // 512 = 4 batches x 16 mt x 8 nt
    int b = i >> 7, r = i & 127;
    int mt = 15 - (r >> 3), nt = r & 7;
    int m0 = mt * 128, n0 = nt * 128;
    const bf16* Pp = P + (long long)b * Ln * Ln;
    const bf16* Bv = VWT + b * Ln;
    float* Co = out + (long long)b * Ln * Cn;
    gemm_core<float>(Pp, Bv, Co, m0, n0, m0 + 128, Ln, 8192, Cn, 1.0f);
}

// ---------------------------------------------------------------------------
// Causal softmax on bf16 S in place (scale folded into g2). One WAVE per row,
// bf16x8 vector loads/stores, wave-level reductions only (no barriers).
// Writes zeros in (q, kmax) so g3's K-clamp (= kmax for every row in the
// m-tile) sums cleanly.
// ---------------------------------------------------------------------------
__device__ __forceinline__ float waveMax(float x) {
#pragma unroll
    for (int o = 32; o > 0; o >>= 1) x = fmaxf(x, __shfl_xor(x, o, 64));
    return x;
}
__device__ __forceinline__ float waveSum(float x) {
#pragma unroll
    for (int o = 32; o > 0; o >>= 1) x += __shfl_xor(x, o, 64);
    return x;
}

__global__ __launch_bounds__(256)
void softmax_causal(bf16* __restrict__ S)
{
    const int wave = threadIdx.x >> 6, lane = threadIdx.x & 63;
    const int row = blockIdx.x * 4 + wave;       // 0..8191 = b*L + q
    const int q = row & (Ln - 1);
    bf16* Srow = S + (long long)row * Ln;
    const int kmax = ((q >> 7) + 1) << 7;
    const int nv = (kmax + 511) >> 9;            // 1..4 chunks of 512 cols

    float x[4][8];
    float m = -1e30f;
    for (int it = 0; it < nv; ++it) {
        int c0 = it * 512 + lane * 8;
        bf16x8 v = *(const bf16x8*)(Srow + c0);
#pragma unroll
        for (int e = 0; e < 8; ++e) {
            float f = (float)v[e];
            f = (c0 + e <= q) ? f : -1e30f;
            x[it][e] = f;
            m = fmaxf(m, f);
        }
    }
    m = waveMax(m);
    float s = 0.f;
    for (int it = 0; it < nv; ++it)
#pragma unroll
        for (int e = 0; e < 8; ++e) {
            float ex = (x[it][e] > -1e29f) ? __expf(x[it][e] - m) : 0.f;
            x[it][e] = ex;
            s += ex;
        }
    s = waveSum(s);
    float inv = 1.f / s;
    for (int it = 0; it < nv; ++it) {
        bf16x8 o;
#pragma unroll
        for (int e = 0; e < 8; ++e) o[e] = (__bf16)(x[it][e] * inv);
        *(bf16x8*)(Srow + it * 512 + lane * 8) = o;
    }
}

// ---------------------------------------------------------------------------
// cast_all: blocks [0,11264)   element-wise fp32->bf16 (X, Wqk rows, Wout)
//           blocks [11264,12288) transpose-cast Wv (1024x1024) -> WvT
// float4-unit region sizes: X 2097152, Wqk 524288, Wout 262144.
// ---------------------------------------------------------------------------
__global__ __launch_bounds__(256)
void cast_all(const float* __restrict__ X, const float* __restrict__ Wqkv,
              const float* __restrict__ Wo,
              bf16* __restrict__ Xb, bf16* __restrict__ Wqkb,
              bf16* __restrict__ Wob, bf16* __restrict__ WvT)
{
    int blk = blockIdx.x;
    if (blk < 11264) {
        int i = blk * 256 + threadIdx.x;
        const float* src; bf16* dst; int off;
        if (i < 2097152)                 { src = X;    dst = Xb;   off = i; }
        else if (i < 2097152 + 524288)   { src = Wqkv; dst = Wqkb; off = i - 2097152; }
        else                             { src = Wo;   dst = Wob;  off = i - 2621440; }
        float4 f = ((const float4*)src)[off];
        bf16 o0 = __float2bfloat16(f.x), o1 = __float2bfloat16(f.y);
        bf16 o2 = __float2bfloat16(f.z), o3 = __float2bfloat16(f.w);
        ushort4 u;
        u.x = *(unsigned short*)&o0; u.y = *(unsigned short*)&o1;
        u.z = *(unsigned short*)&o2; u.w = *(unsigned short*)&o3;
        *(ushort4*)(dst + (size_t)off * 4) = u;
    } else {
        __shared__ float t[32][33];
        int tt = blk - 11264;
        int c0 = (tt & 31) * 32;         // col tile in Wv
        int r0 = (tt >> 5) * 32;         // row tile in Wv
        const float* Wv = Wqkv + 2048 * 1024;
        int xcol = threadIdx.x & 31, y0 = threadIdx.x >> 5;
#pragma unroll
        for (int p = 0; p < 4; ++p) {
            int y = y0 + 8 * p;
            t[y][xcol] = Wv[(size_t)(r0 + y) * 1024 + c0 + xcol];
        }
        __syncthreads();
#pragma unroll
        for (int p = 0; p < 4; ++p) {
            int mloc = y0 + 8 * p;       // WvT[c0+mloc][r0+xcol] = Wv[r0+xcol][c0+mloc]
            WvT[(size_t)(c0 + mloc) * 1024 + r0 + xcol] = __float2bfloat16(t[xcol][mloc]);
        }
    }
}

// ---------------------------------------------------------------------------
extern "C" void kernel_launch(void* const* d_in, const int* in_sizes, int n_in,
                              void* d_out, int out_size, void* d_ws, size_t ws_size,
                              hipStream_t stream)
{
    const float* X    = (const float*)d_in[0];   // (B,L,C)
    const float* Wqkv = (const float*)d_in[1];   // (3C,C)
    const float* Wout = (const float*)d_in[2];   // (C,C)
    float* out = (float*)d_out;                  // (B,L,C) fp32

    char* ws = (char*)d_ws;
    const size_t MiB = 1024ull * 1024ull;
    bf16* Xb   = (bf16*)(ws + 0);                // 16 MiB
    bf16* QK   = (bf16*)(ws + 16 * MiB);         // 32 MiB (q cols 0..1023, k cols 1024..2047)
    bf16* VWT  = (bf16*)(ws + 48 * MiB);         // 16 MiB (1024 x 8192, ld 8192)
    bf16* Sbuf = (bf16*)(ws + 64 * MiB);         // 32 MiB (P in place)
    bf16* Wqkb = (bf16*)(ws + 96 * MiB);         // 4 MiB
    bf16* WvT  = (bf16*)(ws + 100 * MiB);        // 2 MiB
    bf16* Wob  = (bf16*)(ws + 102 * MiB);        // 2 MiB
    bf16* W2   = (bf16*)(ws + 104 * MiB);        // 2 MiB  (total 106 MiB)

    cast_all<<<dim3(12288), 256, 0, stream>>>(X, Wqkv, Wout, Xb, Wqkb, Wob, WvT);

    g1_w2_qk<<<dim3(1088), 256, 0, stream>>>(Xb, Wqkb, Wob, WvT, QK, W2);

    g2_vwt_s<<<dim3(1056), 256, 0, stream>>>(W2, Xb, QK, VWT, Sbuf);

    softmax_causal<<<dim3(Bn * Ln / 4), 256, 0, stream>>>(Sbuf);

    g3_out<<<dim3(512), 256, 0, stream>>>(Sbuf, VWT, out);
}

// Round 5
// 250.890 us; speedup vs baseline: 1.3032x; 1.0839x over previous
//
#include <hip/hip_runtime.h>
#include <hip/hip_bf16.h>
#include <cstdint>
#include <cstddef>

typedef __hip_bfloat16 bf16;
typedef float  floatx4 __attribute__((ext_vector_type(4)));
typedef __bf16 bf16x8  __attribute__((ext_vector_type(8)));

typedef __attribute__((address_space(1))) void as1_void;
typedef __attribute__((address_space(3))) void as3_void;

constexpr int Bn = 4, Ln = 2048, Cn = 1024;

__device__ __forceinline__ void store_one(float* p, float v) { *p = v; }
__device__ __forceinline__ void store_one(bf16*  p, float v) { *p = __float2bfloat16(v); }

// ---------------------------------------------------------------------------
// Core bf16 BT-GEMM tile: C[m0..+128][n0..+128] = cscale * sum_k A[m][k]*B[n][k]
// 256 thr / 4 waves, each wave 64x64 via 4x4 mfma_f32_16x16x32_bf16.
// NOTE (R2 post-mortem): no LDS swizzle — SQ_LDS_BANK_CONFLICT is exactly
// 4/ds_read_b128 regardless (intrinsic wave64 b128 cost, not aliasing).
// NOTE (R4 post-mortem): block->XCD mapping (blockIdx%8 heuristic) dominates
// L2 behavior when a dispatch mixes GEMMs — keep same-B-tile blocks at
// stride-8 indices, pin batches to XCD pairs.
// ---------------------------------------------------------------------------
template <typename OutT>
__device__ __forceinline__ void gemm_core(
    const bf16* __restrict__ A, const bf16* __restrict__ B, OutT* __restrict__ C,
    int m0, int n0, int Keff, int lda, int ldb, int ldc, float cscale)
{
    __shared__ __align__(16) bf16 smem[2 * 128 * 32];   // As (8KB) then Bs (8KB)

    const int tid  = threadIdx.x;
    const int lane = tid & 63;
    const int quad = lane >> 4;
    const int lr   = lane & 15;
    const int wave = tid >> 6;
    const int wm   = (wave >> 1) * 64;
    const int wn   = (wave & 1) * 64;

    floatx4 acc[4][4];
#pragma unroll
    for (int i = 0; i < 4; ++i)
#pragma unroll
        for (int j = 0; j < 4; ++j) { floatx4 z = {0.f, 0.f, 0.f, 0.f}; acc[i][j] = z; }

    // staging: 1024 16B chunks; chunk = it*256 + tid, LDS linear (lane-order).
    const bf16* gbase[4];
    int ldsoff[4];
#pragma unroll
    for (int it = 0; it < 4; ++it) {
        int chunk = it * 256 + tid;
        ldsoff[it] = __builtin_amdgcn_readfirstlane((chunk & ~63) * 16);
        int kc = chunk & 3;
        if (chunk < 512) {               // A side: 4 chunks per 32-elem row
            int m = chunk >> 2;
            gbase[it] = A + (size_t)(m0 + m) * lda + kc * 8;
        } else {                         // B side
            int c2 = chunk - 512;
            int n = c2 >> 2;
            gbase[it] = B + (size_t)(n0 + n) * ldb + kc * 8;
        }
    }

    for (int k0 = 0; k0 < Keff; k0 += 32) {
        __syncthreads();
#pragma unroll
        for (int it = 0; it < 4; ++it) {
            uintptr_t ga = (uintptr_t)(gbase[it] + k0);
            uintptr_t la = (uintptr_t)((char*)smem + ldsoff[it]);
            __builtin_amdgcn_global_load_lds((const as1_void*)ga, (as3_void*)la, 16, 0, 0);
        }
        __syncthreads();

        const bf16* As = smem;
        const bf16* Bs = smem + 128 * 32;
        bf16x8 afrag[4], bfrag[4];
#pragma unroll
        for (int i = 0; i < 4; ++i)
            afrag[i] = *(const bf16x8*)(As + (size_t)(wm + i * 16 + lr) * 32 + quad * 8);
#pragma unroll
        for (int j = 0; j < 4; ++j)
            bfrag[j] = *(const bf16x8*)(Bs + (size_t)(wn + j * 16 + lr) * 32 + quad * 8);
#pragma unroll
        for (int i = 0; i < 4; ++i)
#pragma unroll
            for (int j = 0; j < 4; ++j)
                acc[i][j] = __builtin_amdgcn_mfma_f32_16x16x32_bf16(afrag[i], bfrag[j], acc[i][j], 0, 0, 0);
    }

    // epilogue: C/D layout col=lane&15, row=quad*4+r  (m89-verified)
#pragma unroll
    for (int i = 0; i < 4; ++i) {
        int row = m0 + wm + i * 16 + quad * 4;
#pragma unroll
        for (int j = 0; j < 4; ++j) {
            int col = n0 + wn + j * 16 + lr;
            OutT* cp = C + (size_t)row * ldc + col;
#pragma unroll
            for (int r = 0; r < 4; ++r)
                store_one(cp + (size_t)r * ldc, acc[i][j][r] * cscale);
        }
    }
}

// ---------------------------------------------------------------------------
// g1: blocks [0,64)    -> W2 = Wo·Wv   (1024x1024, K=1024)  [A=Wob, B=WvT]
//     blocks [64,1088) -> QK = Xb·Wqk^T (8192x2048, K=1024)
//     QK indexing: m0 = j&63 (stride-64 blocks share m -> same XCD for Xb rows)
// ---------------------------------------------------------------------------
__global__ __launch_bounds__(256)
void g1_w2_qk(const bf16* __restrict__ Xb, const bf16* __restrict__ Wqkb,
              const bf16* __restrict__ Wob, const bf16* __restrict__ WvT,
              bf16* __restrict__ QK, bf16* __restrict__ W2)
{
    int i = blockIdx.x;
    if (i < 64) {
        int m0 = (i & 7) * 128, n0 = (i >> 3) * 128;
        gemm_core<bf16>(Wob, WvT, W2, m0, n0, 1024, 1024, 1024, 1024, 1.0f);
    } else {
        int j = i - 64;
        int m0 = (j & 63) * 128, n0 = (j >> 6) * 128;
        gemm_core<bf16>(Xb, Wqkb, QK, m0, n0, 1024, 1024, 1024, 2048, 1.0f);
    }
}

// ---------------------------------------------------------------------------
// g2: blocks [0,512)    -> VWT = W2·Xb^T (1024x8192, K=1024, ldc 8192)
//        n0 = (i&63): blocks sharing an Xb n-tile sit at stride 64 -> same XCD.
//     blocks [512,1056) -> S = (Q·K^T)/32, triangular tiles, 136/batch.
//        s = i-512: XCD = s%8 = 2b+p -> batch b pinned to XCD pair {2b,2b+1};
//        stream p walks tiles t = (s>>3)*2+p in ti-order (Q-tile reuse).
// ---------------------------------------------------------------------------
__global__ __launch_bounds__(256)
void g2_vwt_s(const bf16* __restrict__ W2, const bf16* __restrict__ Xb,
              const bf16* __restrict__ QK, bf16* __restrict__ VWT,
              bf16* __restrict__ S)
{
    int i = blockIdx.x;
    if (i < 512) {
        int m0 = (i >> 6) * 128, n0 = (i & 63) * 128;
        gemm_core<bf16>(W2, Xb, VWT, m0, n0, 1024, 1024, 1024, 8192, 1.0f);
    } else {
        int s = i - 512;                 // 0..543
        int b = (s & 7) >> 1;
        int p = s & 1;
        int t = (s >> 3) * 2 + p;        // 0..135
        int ti = (int)((sqrtf(8.f * t + 1.f) - 1.f) * 0.5f);
        while ((ti + 1) * (ti + 2) / 2 <= t) ++ti;
        while (ti * (ti + 1) / 2 > t) --ti;
        int tj = t - ti * (ti + 1) / 2;
        const bf16* Aq = QK + (long long)b * Ln * 2048;
        const bf16* Bk = Aq + 1024;
        bf16* Sb = S + (long long)b * Ln * Ln;
        gemm_core<bf16>(Aq, Bk, Sb, ti * 128, tj * 128, 1024, 2048, 2048, Ln, 0.03125f);
    }
}

// ---------------------------------------------------------------------------
// g3: out = P · VW  (per batch, K clamped to m0+128), fp32 out.
// XCD = i%8 = 2b+p (batch pinned to XCD pair); q = i>>3: mt = 15-(q>>2)
// (heavy tiles first, P m-tile reused by 4 consecutive blocks), nt = p+2*(q&3).
// ---------------------------------------------------------------------------
__global__ __launch_bounds__(256)
void g3_out(const bf16* __restrict__ P, const bf16* __restrict__ VWT,
            float* __restrict__ out)
{
    int i = blockIdx.x;                  // 512
    int r = i & 7, q = i >> 3;
    int b = r >> 1, p = r & 1;
    int mt = 15 - (q >> 2), nt = p + 2 * (q & 3);
    int m0 = mt * 128, n0 = nt * 128;
    const bf16* Pp = P + (long long)b * Ln * Ln;
    const bf16* Bv = VWT + b * Ln;
    float* Co = out + (long long)b * Ln * Cn;
    gemm_core<float>(Pp, Bv, Co, m0, n0, m0 + 128, Ln, 8192, Cn, 1.0f);
}

// ---------------------------------------------------------------------------
// Causal softmax on bf16 S in place (scale folded into g2). One WAVE per row,
// bf16x8 vector loads/stores, wave-level reductions only (no barriers).
// ---------------------------------------------------------------------------
__device__ __forceinline__ float waveMax(float x) {
#pragma unroll
    for (int o = 32; o > 0; o >>= 1) x = fmaxf(x, __shfl_xor(x, o, 64));
    return x;
}
__device__ __forceinline__ float waveSum(float x) {
#pragma unroll
    for (int o = 32; o > 0; o >>= 1) x += __shfl_xor(x, o, 64);
    return x;
}

__global__ __launch_bounds__(256)
void softmax_causal(bf16* __restrict__ S)
{
    const int wave = threadIdx.x >> 6, lane = threadIdx.x & 63;
    const int row = blockIdx.x * 4 + wave;       // 0..8191 = b*L + q
    const int q = row & (Ln - 1);
    bf16* Srow = S + (long long)row * Ln;
    const int kmax = ((q >> 7) + 1) << 7;
    const int nv = (kmax + 511) >> 9;            // 1..4 chunks of 512 cols

    float x[4][8];
    float m = -1e30f;
    for (int it = 0; it < nv; ++it) {
        int c0 = it * 512 + lane * 8;
        bf16x8 v = *(const bf16x8*)(Srow + c0);
#pragma unroll
        for (int e = 0; e < 8; ++e) {
            float f = (float)v[e];
            f = (c0 + e <= q) ? f : -1e30f;
            x[it][e] = f;
            m = fmaxf(m, f);
        }
    }
    m = waveMax(m);
    float s = 0.f;
    for (int it = 0; it < nv; ++it)
#pragma unroll
        for (int e = 0; e < 8; ++e) {
            float ex = (x[it][e] > -1e29f) ? __expf(x[it][e] - m) : 0.f;
            x[it][e] = ex;
            s += ex;
        }
    s = waveSum(s);
    float inv = 1.f / s;
    for (int it = 0; it < nv; ++it) {
        bf16x8 o;
#pragma unroll
        for (int e = 0; e < 8; ++e) o[e] = (__bf16)(x[it][e] * inv);
        *(bf16x8*)(Srow + it * 512 + lane * 8) = o;
    }
}

// ---------------------------------------------------------------------------
// cast_all: blocks [0,11264)   element-wise fp32->bf16 (X, Wqk rows, Wout)
//           blocks [11264,12288) transpose-cast Wv (1024x1024) -> WvT
// ---------------------------------------------------------------------------
__global__ __launch_bounds__(256)
void cast_all(const float* __restrict__ X, const float* __restrict__ Wqkv,
              const float* __restrict__ Wo,
              bf16* __restrict__ Xb, bf16* __restrict__ Wqkb,
              bf16* __restrict__ Wob, bf16* __restrict__ WvT)
{
    int blk = blockIdx.x;
    if (blk < 11264) {
        int i = blk * 256 + threadIdx.x;
        const float* src; bf16* dst; int off;
        if (i < 2097152)                 { src = X;    dst = Xb;   off = i; }
        else if (i < 2097152 + 524288)   { src = Wqkv; dst = Wqkb; off = i - 2097152; }
        else                             { src = Wo;   dst = Wob;  off = i - 2621440; }
        float4 f = ((const float4*)src)[off];
        bf16 o0 = __float2bfloat16(f.x), o1 = __float2bfloat16(f.y);
        bf16 o2 = __float2bfloat16(f.z), o3 = __float2bfloat16(f.w);
        ushort4 u;
        u.x = *(unsigned short*)&o0; u.y = *(unsigned short*)&o1;
        u.z = *(unsigned short*)&o2; u.w = *(unsigned short*)&o3;
        *(ushort4*)(dst + (size_t)off * 4) = u;
    } else {
        __shared__ float t[32][33];
        int tt = blk - 11264;
        int c0 = (tt & 31) * 32;         // col tile in Wv
        int r0 = (tt >> 5) * 32;         // row tile in Wv
        const float* Wv = Wqkv + 2048 * 1024;
        int xcol = threadIdx.x & 31, y0 = threadIdx.x >> 5;
#pragma unroll
        for (int p = 0; p < 4; ++p) {
            int y = y0 + 8 * p;
            t[y][xcol] = Wv[(size_t)(r0 + y) * 1024 + c0 + xcol];
        }
        __syncthreads();
#pragma unroll
        for (int p = 0; p < 4; ++p) {
            int mloc = y0 + 8 * p;       // WvT[c0+mloc][r0+xcol] = Wv[r0+xcol][c0+mloc]
            WvT[(size_t)(c0 + mloc) * 1024 + r0 + xcol] = __float2bfloat16(t[xcol][mloc]);
        }
    }
}

// ---------------------------------------------------------------------------
extern "C" void kernel_launch(void* const* d_in, const int* in_sizes, int n_in,
                              void* d_out, int out_size, void* d_ws, size_t ws_size,
                              hipStream_t stream)
{
    const float* X    = (const float*)d_in[0];   // (B,L,C)
    const float* Wqkv = (const float*)d_in[1];   // (3C,C)
    const float* Wout = (const float*)d_in[2];   // (C,C)
    float* out = (float*)d_out;                  // (B,L,C) fp32

    char* ws = (char*)d_ws;
    const size_t MiB = 1024ull * 1024ull;
    bf16* Xb   = (bf16*)(ws + 0);                // 16 MiB
    bf16* QK   = (bf16*)(ws + 16 * MiB);         // 32 MiB (q cols 0..1023, k cols 1024..2047)
    bf16* VWT  = (bf16*)(ws + 48 * MiB);         // 16 MiB (1024 x 8192, ld 8192)
    bf16* Sbuf = (bf16*)(ws + 64 * MiB);         // 32 MiB (P in place)
    bf16* Wqkb = (bf16*)(ws + 96 * MiB);         // 4 MiB
    bf16* WvT  = (bf16*)(ws + 100 * MiB);        // 2 MiB
    bf16* Wob  = (bf16*)(ws + 102 * MiB);        // 2 MiB
    bf16* W2   = (bf16*)(ws + 104 * MiB);        // 2 MiB  (total 106 MiB)

    cast_all<<<dim3(12288), 256, 0, stream>>>(X, Wqkv, Wout, Xb, Wqkb, Wob, WvT);

    g1_w2_qk<<<dim3(1088), 256, 0, stream>>>(Xb, Wqkb, Wob, WvT, QK, W2);

    g2_vwt_s<<<dim3(1056), 256, 0, stream>>>(W2, Xb, QK, VWT, Sbuf);

    softmax_causal<<<dim3(Bn * Ln / 4), 256, 0, stream>>>(Sbuf);

    g3_out<<<dim3(512), 256, 0, stream>>>(Sbuf, VWT, out);
}